// Round 7
// baseline (601.575 us; speedup 1.0000x reference)
//
#include <hip/hip_runtime.h>

#define DM 128
#define NH 8
#define DFF 512
#define MT 32           // ff_fused M-tile rows

typedef __attribute__((ext_vector_type(8))) short bf16x8;
typedef __attribute__((ext_vector_type(4))) float f32x4;

__device__ __forceinline__ short f2bf(float f) {
    union { float f; unsigned u; } v; v.f = f;
    unsigned r = v.u + 0x7fffu + ((v.u >> 16) & 1u);   // RNE
    return (short)(r >> 16);
}
__device__ __forceinline__ float bf2f(unsigned short b) {
    union { unsigned u; float f; } v; v.u = ((unsigned)b) << 16; return v.f;
}

// ---------------------------------------------------------------------------
// LDS-free bf16 MFMA GEMM (layer-0 z projection only). C = A[M,K] @ BT[Nc,K]^T.
// ---------------------------------------------------------------------------
template<int K>
__global__ __launch_bounds__(256) void gemm_direct(
    const short* __restrict__ A, const short* __restrict__ BT,
    int M, int Nc, short* __restrict__ Cbf)
{
    constexpr int nK = K / 32;
    const int tid = threadIdx.x;
    const int wave = tid >> 6, lane = tid & 63;
    const int wm = wave >> 1, wn = wave & 1;
    const int bm = blockIdx.y * 128, bn = blockIdx.x * 128;
    const int fr = lane & 15;
    const int fk = (lane >> 4) << 3;

    const short* Ab[4];
    const short* Bb[4];
#pragma unroll
    for (int i = 0; i < 4; ++i) {
        int row = bm + wm * 64 + i * 16 + fr;
        row = (row < M) ? row : (M - 1);
        Ab[i] = A + (size_t)row * K + fk;
    }
#pragma unroll
    for (int j = 0; j < 4; ++j) {
        int col = bn + wn * 64 + j * 16 + fr;
        Bb[j] = BT + (size_t)col * K + fk;
    }

    f32x4 acc[4][4];
#pragma unroll
    for (int i = 0; i < 4; ++i)
#pragma unroll
        for (int j = 0; j < 4; ++j) acc[i][j] = (f32x4)0.0f;

#pragma unroll
    for (int ks = 0; ks < nK; ++ks) {
        bf16x8 af[4], bfr[4];
#pragma unroll
        for (int i = 0; i < 4; ++i) {
            af[i]  = *(const bf16x8*)(Ab[i] + ks * 32);
            bfr[i] = *(const bf16x8*)(Bb[i] + ks * 32);
        }
#pragma unroll
        for (int i = 0; i < 4; ++i)
#pragma unroll
            for (int j = 0; j < 4; ++j)
                acc[i][j] = __builtin_amdgcn_mfma_f32_16x16x32_bf16(
                    af[i], bfr[j], acc[i][j], 0, 0, 0);
    }

    const int row0 = bm + wm * 64;
    const int col0 = bn + wn * 64;
    const int lr = (lane >> 4) * 4;
    const int lc = lane & 15;
#pragma unroll
    for (int i = 0; i < 4; ++i)
#pragma unroll
        for (int r = 0; r < 4; ++r) {
            int row = row0 + i * 16 + lr + r;
            if (row >= M) continue;
#pragma unroll
            for (int j = 0; j < 4; ++j) {
                int col = col0 + j * 16 + lc;
                Cbf[(size_t)row * Nc + col] = f2bf(acc[i][j][r]);
            }
        }
}

// ---------------------------------------------------------------------------
// Fused FF + next-layer projection, one block per 32-row tile.
//  G1: ffh = prelu(hn @ W1 + b1) -> LDS (MFMA-fragment order, conflict-free)
//  G2: xo  = ffh @ W2 + b2 + h (fp32) ; x-tile -> same LDS buffer (reused)
//  G3: z'  = xo @ Wnext (bf16)
// LDS = exactly 32 KB -> 5 blocks/CU; __launch_bounds__(256,5) caps VGPR.
// Fragment-order address for (row 0..31, k): frag f=(k>>5)*2+(row>>4),
// lane'=(row&15)+(((k>>3)&3)... within frag: lane' = (row&15)+((k&31)>>3)*16,
// elem k&7 -> sF[f*512 + lane'*8 + (k&7)].
// ---------------------------------------------------------------------------
__global__ __launch_bounds__(256, 5) void ff_fused(
    const short* __restrict__ hn, const short* __restrict__ W1t,
    const short* __restrict__ W2t, const short* __restrict__ h_bf,
    const float* __restrict__ b1, const float* __restrict__ b2,
    const float* __restrict__ a_ff, float* __restrict__ xo,
    const short* __restrict__ Wnt, short* __restrict__ z_next, int M)
{
    __shared__ short sF[16384];   // 32768 B; ffh tile, then reused as x tile

    const int tid = threadIdx.x;
    const int wave = tid >> 6, lane = tid & 63;
    const int m0 = blockIdx.x * MT;
    const int fr  = lane & 15;
    const int fk8 = (lane >> 4) << 3;
    const int lr4 = (lane >> 4) << 2;
    const int lc  = lane & 15;

    // ---------------- G1: acc1 = hn @ W1 ----------------
    f32x4 acc1[2][8];
#pragma unroll
    for (int rg = 0; rg < 2; ++rg)
#pragma unroll
        for (int cg = 0; cg < 8; ++cg) acc1[rg][cg] = (f32x4)0.0f;

    const short* w1base = W1t + (size_t)(wave * 128 + fr) * DM + fk8;
    int arow0 = m0 + fr;      arow0 = (arow0 < M) ? arow0 : (M - 1);
    int arow1 = m0 + 16 + fr; arow1 = (arow1 < M) ? arow1 : (M - 1);
    const short* ab0 = hn + (size_t)arow0 * DM + fk8;
    const short* ab1 = hn + (size_t)arow1 * DM + fk8;

#pragma unroll
    for (int ks = 0; ks < 4; ++ks) {
        bf16x8 a0 = *(const bf16x8*)(ab0 + ks * 32);
        bf16x8 a1 = *(const bf16x8*)(ab1 + ks * 32);
#pragma unroll
        for (int half = 0; half < 2; ++half) {
            bf16x8 bfr[4];
#pragma unroll
            for (int c = 0; c < 4; ++c)
                bfr[c] = *(const bf16x8*)(w1base + (size_t)(half * 4 + c) * 16 * DM + ks * 32);
#pragma unroll
            for (int c = 0; c < 4; ++c) {
                acc1[0][half * 4 + c] = __builtin_amdgcn_mfma_f32_16x16x32_bf16(
                    a0, bfr[c], acc1[0][half * 4 + c], 0, 0, 0);
                acc1[1][half * 4 + c] = __builtin_amdgcn_mfma_f32_16x16x32_bf16(
                    a1, bfr[c], acc1[1][half * 4 + c], 0, 0, 0);
            }
        }
    }

    // epilogue -> fragment-order LDS
    float aff = *a_ff;
#pragma unroll
    for (int rg = 0; rg < 2; ++rg)
#pragma unroll
        for (int cg = 0; cg < 8; ++cg) {
            int colL = wave * 128 + cg * 16 + lc;
            float bb = b1[colL];
            int ks = colL >> 5;                       // 0..15
            int sub = (cg & 1) * 16 + lc;             // colL & 31
            int lbase = ((ks * 2 + rg) << 9) + ((sub >> 3) << 4) * 8 + (sub & 7);
#pragma unroll
            for (int r = 0; r < 4; ++r) {
                float v = acc1[rg][cg][r] + bb;
                v = (v >= 0.0f) ? v : aff * v;
                sF[lbase + (lr4 + r) * 8] = f2bf(v);
            }
        }
    __syncthreads();

    // residual prefetch (overlaps G2 MFMA loop)
    unsigned short hres[2][2][4];
#pragma unroll
    for (int rg = 0; rg < 2; ++rg)
#pragma unroll
        for (int cg = 0; cg < 2; ++cg) {
            int colL = wave * 32 + cg * 16 + lc;
#pragma unroll
            for (int r = 0; r < 4; ++r) {
                int row = m0 + rg * 16 + lr4 + r;
                int rc = (row < M) ? row : (M - 1);
                hres[rg][cg][r] = (unsigned short)h_bf[(size_t)rc * DM + colL];
            }
        }

    // ---------------- G2: xo = ffh @ W2 + b2 + h ----------------
    f32x4 acc2[2][2];
#pragma unroll
    for (int rg = 0; rg < 2; ++rg)
#pragma unroll
        for (int cg = 0; cg < 2; ++cg) acc2[rg][cg] = (f32x4)0.0f;

    const short* w2base = W2t + (size_t)(wave * 32 + fr) * DFF + fk8;
#pragma unroll
    for (int ks = 0; ks < 16; ++ks) {
        bf16x8 a2[2], b2f[2];
#pragma unroll
        for (int rg = 0; rg < 2; ++rg)
            a2[rg] = *(const bf16x8*)(sF + ((ks * 2 + rg) << 9) + lane * 8);
#pragma unroll
        for (int cg = 0; cg < 2; ++cg)
            b2f[cg] = *(const bf16x8*)(w2base + (size_t)cg * 16 * DFF + ks * 32);
#pragma unroll
        for (int rg = 0; rg < 2; ++rg)
#pragma unroll
            for (int cg = 0; cg < 2; ++cg)
                acc2[rg][cg] = __builtin_amdgcn_mfma_f32_16x16x32_bf16(
                    a2[rg], b2f[cg], acc2[rg][cg], 0, 0, 0);
    }

    // compute xo values, write global
    float vx[2][2][4];
#pragma unroll
    for (int rg = 0; rg < 2; ++rg)
#pragma unroll
        for (int cg = 0; cg < 2; ++cg) {
            int colL = wave * 32 + cg * 16 + lc;
            float bb = b2[colL];
#pragma unroll
            for (int r = 0; r < 4; ++r) {
                int row = m0 + rg * 16 + lr4 + r;
                float v = acc2[rg][cg][r] + bb + bf2f(hres[rg][cg][r]);
                vx[rg][cg][r] = v;
                if (row < M) xo[(size_t)row * DM + colL] = v;
            }
        }

    if (Wnt == nullptr) return;

    __syncthreads();    // all sF reads done -> safe to overwrite
    // stage x tile into sF (fragment order, k range 0..127 -> frags 0..7)
#pragma unroll
    for (int rg = 0; rg < 2; ++rg)
#pragma unroll
        for (int cg = 0; cg < 2; ++cg) {
            int colL = wave * 32 + cg * 16 + lc;
            int ks3 = colL >> 5;                      // = wave
            int sub = cg * 16 + lc;
            int lbase = ((ks3 * 2 + rg) << 9) + ((sub >> 3) << 4) * 8 + (sub & 7);
#pragma unroll
            for (int r = 0; r < 4; ++r)
                sF[lbase + (lr4 + r) * 8] = f2bf(vx[rg][cg][r]);
        }
    __syncthreads();

    // ---------------- G3: z' = xo @ Wnext ----------------
    f32x4 acc3[2][2];
#pragma unroll
    for (int rg = 0; rg < 2; ++rg)
#pragma unroll
        for (int cg = 0; cg < 2; ++cg) acc3[rg][cg] = (f32x4)0.0f;

    const short* wnb = Wnt + (size_t)(wave * 32 + fr) * DM + fk8;
#pragma unroll
    for (int ks = 0; ks < 4; ++ks) {
        bf16x8 a3[2], b3[2];
#pragma unroll
        for (int rg = 0; rg < 2; ++rg)
            a3[rg] = *(const bf16x8*)(sF + ((ks * 2 + rg) << 9) + lane * 8);
#pragma unroll
        for (int cg = 0; cg < 2; ++cg)
            b3[cg] = *(const bf16x8*)(wnb + (size_t)cg * 16 * DM + ks * 32);
#pragma unroll
        for (int rg = 0; rg < 2; ++rg)
#pragma unroll
            for (int cg = 0; cg < 2; ++cg)
                acc3[rg][cg] = __builtin_amdgcn_mfma_f32_16x16x32_bf16(
                    a3[rg], b3[cg], acc3[rg][cg], 0, 0, 0);
    }
#pragma unroll
    for (int rg = 0; rg < 2; ++rg)
#pragma unroll
        for (int cg = 0; cg < 2; ++cg) {
            int colL = wave * 32 + cg * 16 + lc;
#pragma unroll
            for (int r = 0; r < 4; ++r) {
                int row = m0 + rg * 16 + lr4 + r;
                if (row < M)
                    z_next[(size_t)row * DM + colL] = f2bf(acc3[rg][cg][r]);
            }
        }
}

// transpose + fp32->bf16 for all L layers: out[l][c][r] = bf16(in[l][r][c])
__global__ void wt_conv_kernel(const float* __restrict__ in, short* __restrict__ out,
                               int R, int C, int nL)
{
    int idx = blockIdx.x * blockDim.x + threadIdx.x;
    if (idx >= nL * R * C) return;
    int l = idx / (R * C);
    int rem = idx - l * (R * C);
    int r = rem / C, c = rem - r * C;
    out[(size_t)l * R * C + (size_t)c * R + r] = f2bf(in[idx]);
}

__global__ void f2bf_kernel(const float* __restrict__ in, short* __restrict__ out, int n)
{
    int idx = blockIdx.x * blockDim.x + threadIdx.x;
    if (idx < n) out[idx] = f2bf(in[idx]);
}

// el/er from bf16 z
__global__ void el_er_kernel(const short* __restrict__ z,
                             const float* __restrict__ al,
                             const float* __restrict__ ar,
                             float* __restrict__ el, float* __restrict__ er, int N)
{
    int idx = blockIdx.x * blockDim.x + threadIdx.x;
    if (idx >= N * NH) return;
    int n = idx >> 3, h = idx & 7;
    const unsigned* zp = (const unsigned*)(z + (size_t)n * DM + h * 16);
    const float* alp = al + h * 16;
    const float* arp = ar + h * 16;
    float sl = 0.0f, sr = 0.0f;
#pragma unroll
    for (int d2 = 0; d2 < 8; ++d2) {
        unsigned u = zp[d2];
        float z0 = bf2f((unsigned short)(u & 0xffff));
        float z1 = bf2f((unsigned short)(u >> 16));
        sl = fmaf(z0, alp[2 * d2], sl);     sl = fmaf(z1, alp[2 * d2 + 1], sl);
        sr = fmaf(z0, arp[2 * d2], sr);     sr = fmaf(z1, arp[2 * d2 + 1], sr);
    }
    el[idx] = sl;
    er[idx] = sr;
}

// ---------------- CSR build ----------------
__global__ void hist_kernel(const int* __restrict__ dst, int* __restrict__ deg, int E)
{
    int e = blockIdx.x * blockDim.x + threadIdx.x;
    if (e < E) atomicAdd(&deg[dst[e]], 1);
}

__global__ void scan1_kernel(const int* __restrict__ deg, int* __restrict__ incl,
                             int* __restrict__ bsum, int N)
{
    __shared__ int sm[256];
    int i = blockIdx.x * 256 + threadIdx.x;
    int v = (i < N) ? deg[i] : 0;
    sm[threadIdx.x] = v;
    __syncthreads();
    for (int off = 1; off < 256; off <<= 1) {
        int t = (threadIdx.x >= off) ? sm[threadIdx.x - off] : 0;
        __syncthreads();
        sm[threadIdx.x] += t;
        __syncthreads();
    }
    if (i < N) incl[i] = sm[threadIdx.x];
    if (threadIdx.x == 255) bsum[blockIdx.x] = sm[255];
}

__global__ void scan2_kernel(int* __restrict__ bsum, int nb)
{
    __shared__ int sm[256];
    int v = (threadIdx.x < nb) ? bsum[threadIdx.x] : 0;
    sm[threadIdx.x] = v;
    __syncthreads();
    for (int off = 1; off < 256; off <<= 1) {
        int t = (threadIdx.x >= off) ? sm[threadIdx.x - off] : 0;
        __syncthreads();
        sm[threadIdx.x] += t;
        __syncthreads();
    }
    if (threadIdx.x < nb) bsum[threadIdx.x] = sm[threadIdx.x];
}

__global__ void scan3_kernel(const int* __restrict__ incl, const int* __restrict__ bsum,
                             int* __restrict__ row_ptr, int N)
{
    int i = blockIdx.x * 256 + threadIdx.x;
    if (i < N) {
        int off = (blockIdx.x > 0) ? bsum[blockIdx.x - 1] : 0;
        row_ptr[i + 1] = incl[i] + off;
    }
    if (i == 0) row_ptr[0] = 0;
}

__global__ void scatter_kernel(const int* __restrict__ src, const int* __restrict__ dst,
                               const int* __restrict__ row_ptr, int* __restrict__ cursor,
                               int* __restrict__ csr_src, int E)
{
    int e = blockIdx.x * blockDim.x + threadIdx.x;
    if (e >= E) return;
    int t = dst[e];
    int pos = atomicAdd(&cursor[t], 1);
    csr_src[row_ptr[t] + pos] = src[e];
}

// ---------------------------------------------------------------------------
// Fused: edge-softmax + aggregate (bf16 z) + conv bias + PReLU + LN1 + LN2.
// One wave per dst node. Fast path deg<=16: issue ALL edge chains' loads in
// one latency round (clamped index, predicated accumulate).
// ---------------------------------------------------------------------------
__global__ __launch_bounds__(256) void gat_agg_ln_kernel(
    const int* __restrict__ row_ptr, const int* __restrict__ csr_src,
    const short* __restrict__ z, const float* __restrict__ el,
    const float* __restrict__ er, const float* __restrict__ cb,
    const float* __restrict__ a_conv,
    const float* __restrict__ scale, const float* __restrict__ bias,
    short* __restrict__ h_out, short* __restrict__ hn_out, int N)
{
    int wave = threadIdx.x >> 6, lane = threadIdx.x & 63;
    int t = blockIdx.x * 4 + wave;
    if (t >= N) return;
    int h = lane >> 3;
    int c0 = 2 * lane, c1 = c0 + 1;
    float er_t = er[t * NH + h];
    int e0 = row_ptr[t], e1 = row_ptr[t + 1];
    int d = e1 - e0;
    float acc0 = 0.0f, acc1 = 0.0f, den = 0.0f;
    const unsigned* zw = (const unsigned*)z;

    if (d > 0 && d <= 16) {
        int s[16];
#pragma unroll
        for (int k = 0; k < 16; ++k) s[k] = csr_src[e0 + ((k < d) ? k : 0)];
        float x[16]; unsigned u[16];
#pragma unroll
        for (int k = 0; k < 16; ++k) x[k] = el[s[k] * NH + h];
#pragma unroll
        for (int k = 0; k < 16; ++k) u[k] = zw[(size_t)s[k] * 64 + lane];
#pragma unroll
        for (int k = 0; k < 16; ++k) {
            if (k < d) {
                float v = x[k] + er_t;
                v = (v >= 0.0f) ? v : 0.2f * v;
                float w = __expf(v);
                den += w;
                acc0 = fmaf(w, bf2f((unsigned short)(u[k] & 0xffff)), acc0);
                acc1 = fmaf(w, bf2f((unsigned short)(u[k] >> 16)),   acc1);
            }
        }
    } else if (d > 16) {
        int e = e0;
        for (; e + 8 <= e1; e += 8) {
            int s[8];
#pragma unroll
            for (int k = 0; k < 8; ++k) s[k] = csr_src[e + k];
            float x[8]; unsigned u[8];
#pragma unroll
            for (int k = 0; k < 8; ++k) x[k] = el[s[k] * NH + h];
#pragma unroll
            for (int k = 0; k < 8; ++k) u[k] = zw[(size_t)s[k] * 64 + lane];
#pragma unroll
            for (int k = 0; k < 8; ++k) {
                float v = x[k] + er_t;
                v = (v >= 0.0f) ? v : 0.2f * v;
                float w = __expf(v);
                den += w;
                acc0 = fmaf(w, bf2f((unsigned short)(u[k] & 0xffff)), acc0);
                acc1 = fmaf(w, bf2f((unsigned short)(u[k] >> 16)),   acc1);
            }
        }
        for (; e < e1; ++e) {
            int s = csr_src[e];
            float v = el[s * NH + h] + er_t;
            v = (v >= 0.0f) ? v : 0.2f * v;
            float w = __expf(v);
            den += w;
            unsigned u = zw[(size_t)s * 64 + lane];
            acc0 = fmaf(w, bf2f((unsigned short)(u & 0xffff)), acc0);
            acc1 = fmaf(w, bf2f((unsigned short)(u >> 16)), acc1);
        }
    }

    float a = *a_conv;
    float inv = 1.0f / fmaxf(den, 1e-9f);
    float o0 = acc0 * inv + cb[c0];
    float o1 = acc1 * inv + cb[c1];
    o0 = (o0 >= 0.0f) ? o0 : a * o0;
    o1 = (o1 >= 0.0f) ? o1 : a * o1;

    float sc0 = scale[c0], sc1 = scale[c1];
    float bi0 = bias[c0], bi1 = bias[c1];

    // LN1
    float s1 = o0 + o1, ss = o0 * o0 + o1 * o1;
#pragma unroll
    for (int off = 32; off > 0; off >>= 1) {
        s1 += __shfl_xor(s1, off, 64);
        ss += __shfl_xor(ss, off, 64);
    }
    float mean = s1 * (1.0f / 128.0f);
    float var = ss * (1.0f / 128.0f) - mean * mean;
    float rstd = rsqrtf(var + 1e-5f);
    float h0 = (o0 - mean) * rstd * sc0 + bi0;
    float h1 = (o1 - mean) * rstd * sc1 + bi1;
    unsigned hlo = (unsigned short)f2bf(h0);
    unsigned hhi = (unsigned short)f2bf(h1);
    ((unsigned*)h_out)[(size_t)t * 64 + lane] = hlo | (hhi << 16);

    // LN2
    s1 = h0 + h1; ss = h0 * h0 + h1 * h1;
#pragma unroll
    for (int off = 32; off > 0; off >>= 1) {
        s1 += __shfl_xor(s1, off, 64);
        ss += __shfl_xor(ss, off, 64);
    }
    mean = s1 * (1.0f / 128.0f);
    var = ss * (1.0f / 128.0f) - mean * mean;
    rstd = rsqrtf(var + 1e-5f);
    unsigned lo = (unsigned short)f2bf((h0 - mean) * rstd * sc0 + bi0);
    unsigned hi = (unsigned short)f2bf((h1 - mean) * rstd * sc1 + bi1);
    ((unsigned*)hn_out)[(size_t)t * 64 + lane] = lo | (hi << 16);
}

extern "C" void kernel_launch(void* const* d_in, const int* in_sizes, int n_in,
                              void* d_out, int out_size, void* d_ws, size_t ws_size,
                              hipStream_t stream)
{
    const float* in_feats = (const float*)d_in[0];
    const int*   src      = (const int*)d_in[1];
    const int*   dst      = (const int*)d_in[2];
    const float* W        = (const float*)d_in[3];
    const float* attn_l   = (const float*)d_in[4];
    const float* attn_r   = (const float*)d_in[5];
    const float* convb    = (const float*)d_in[6];
    const float* a_conv   = (const float*)d_in[7];
    const float* ln_scale = (const float*)d_in[8];
    const float* ln_bias  = (const float*)d_in[9];
    const float* W1       = (const float*)d_in[10];
    const float* b1       = (const float*)d_in[11];
    const float* W2       = (const float*)d_in[12];
    const float* b2       = (const float*)d_in[13];
    const float* a_ff     = (const float*)d_in[14];
    float* out = (float*)d_out;

    const int N = in_sizes[0] / DM;
    const int E = in_sizes[1];
    const int L = in_sizes[7];

    char* wsb = (char*)d_ws;
    size_t off = 0;
    auto alloc = [&](size_t bytes) { char* p = wsb + off; off += (bytes + 255) & ~(size_t)255; return p; };

    short* z_bf  = (short*)alloc((size_t)N * DM * sizeof(short));
    short* h_bf  = (short*)alloc((size_t)N * DM * sizeof(short));
    short* hn_bf = (short*)alloc((size_t)N * DM * sizeof(short));
    short* x_bf  = (short*)alloc((size_t)N * DM * sizeof(short));
    float* el    = (float*)alloc((size_t)N * NH * sizeof(float));
    float* er    = (float*)alloc((size_t)N * NH * sizeof(float));
    short* Wt    = (short*)alloc((size_t)L * DM * DM * sizeof(short));
    short* W1t   = (short*)alloc((size_t)L * DFF * DM * sizeof(short));
    short* W2t   = (short*)alloc((size_t)L * DM * DFF * sizeof(short));
    int* deg     = (int*)alloc((size_t)N * sizeof(int));
    int* incl    = (int*)alloc((size_t)N * sizeof(int));
    int* bsum    = (int*)alloc(256 * sizeof(int));
    int* row_ptr = (int*)alloc((size_t)(N + 1) * sizeof(int));
    int* cursor  = (int*)alloc((size_t)N * sizeof(int));
    int* csr_src = (int*)alloc((size_t)E * sizeof(int));

    const int gM128 = (N + 127) / 128;
    const int gMT = (N + MT - 1) / MT;
    const int nbScan = (N + 255) / 256;

    // ---- CSR by dst ----
    hipMemsetAsync(deg, 0, (size_t)N * sizeof(int), stream);
    hipMemsetAsync(cursor, 0, (size_t)N * sizeof(int), stream);
    hist_kernel<<<(E + 255) / 256, 256, 0, stream>>>(dst, deg, E);
    scan1_kernel<<<nbScan, 256, 0, stream>>>(deg, incl, bsum, N);
    scan2_kernel<<<1, 256, 0, stream>>>(bsum, nbScan);
    scan3_kernel<<<nbScan, 256, 0, stream>>>(incl, bsum, row_ptr, N);
    scatter_kernel<<<(E + 255) / 256, 256, 0, stream>>>(src, dst, row_ptr, cursor, csr_src, E);

    // ---- weight convert+transpose, input convert ----
    wt_conv_kernel<<<(L * DM * DM + 255) / 256, 256, 0, stream>>>(W, Wt, DM, DM, L);
    wt_conv_kernel<<<(L * DM * DFF + 255) / 256, 256, 0, stream>>>(W1, W1t, DM, DFF, L);
    wt_conv_kernel<<<(L * DFF * DM + 255) / 256, 256, 0, stream>>>(W2, W2t, DFF, DM, L);
    f2bf_kernel<<<(N * DM + 255) / 256, 256, 0, stream>>>(in_feats, x_bf, N * DM);

    // layer-0 z projection
    gemm_direct<DM><<<dim3(1, gM128), 256, 0, stream>>>(
        x_bf, Wt, N, DM, z_bf);

    for (int l = 0; l < L; ++l) {
        float* xo = out + (size_t)l * N * DM;
        const short* Wnt = (l + 1 < L) ? (Wt + (size_t)(l + 1) * DM * DM) : nullptr;

        el_er_kernel<<<(N * NH + 255) / 256, 256, 0, stream>>>(
            z_bf, attn_l + (size_t)l * NH * 16, attn_r + (size_t)l * NH * 16, el, er, N);

        gat_agg_ln_kernel<<<(N + 3) / 4, 256, 0, stream>>>(
            row_ptr, csr_src, z_bf, el, er, convb + (size_t)l * DM, a_conv + l,
            ln_scale + (size_t)l * DM, ln_bias + (size_t)l * DM, h_bf, hn_bf, N);

        // xo = prelu(hn@W1+b1)@W2 + b2 + h ; z_bf = xo @ W[l+1] (if any)
        ff_fused<<<gMT, 256, 0, stream>>>(
            hn_bf, W1t + (size_t)l * DFF * DM, W2t + (size_t)l * DM * DFF,
            h_bf, b1 + (size_t)l * DFF, b2 + (size_t)l * DM, a_ff + l,
            xo, Wnt, z_bf, N);
    }
}